// Round 2
// baseline (736.430 us; speedup 1.0000x reference)
//
#include <hip/hip_runtime.h>
#include <hip/hip_bf16.h>

// Problem constants
#define BB   64
#define CIN  3
#define HH   224
#define WW   224
#define C1   32
#define H1   112
#define W1   112
#define C2   64
#define H2   56
#define W2   56
#define FEATN 64
#define OUTN 1024
#define K3TOT (FEATN*FEATN*FEATN)   // 262144

typedef __bf16 bf16x8 __attribute__((ext_vector_type(8)));
typedef float  f32x4  __attribute__((ext_vector_type(4)));

// ---------------- conv1: (64,3,224,224) -> relu -> (64,32,112,112), s=2 p=1 ----
__global__ __launch_bounds__(256) void conv1_kernel(const float* __restrict__ x,
        const float* __restrict__ w1, const float* __restrict__ b1,
        float* __restrict__ h1) {
    int pos = blockIdx.x * 256 + threadIdx.x;        // 64*112*112 = 802816
    int b   = pos / (H1 * W1);
    int rem = pos - b * (H1 * W1);
    int oy  = rem / W1;
    int ox  = rem - oy * W1;
    int iy0 = oy * 2 - 1, ix0 = ox * 2 - 1;

    float win[27];
    #pragma unroll
    for (int c = 0; c < CIN; ++c)
      #pragma unroll
      for (int dy = 0; dy < 3; ++dy)
        #pragma unroll
        for (int dx = 0; dx < 3; ++dx) {
          int iy = iy0 + dy, ix = ix0 + dx;
          bool ok = (iy >= 0) & (iy < HH) & (ix >= 0) & (ix < WW);
          win[c*9 + dy*3 + dx] = ok ? x[((b*CIN + c)*HH + iy)*WW + ix] : 0.f;
        }

    #pragma unroll 4
    for (int oc = 0; oc < C1; ++oc) {
      float acc = b1[oc];
      #pragma unroll
      for (int q = 0; q < 27; ++q)
        acc = fmaf(w1[oc*27 + q], win[q], acc);
      h1[((b*C1 + oc)*H1 + oy)*W1 + ox] = fmaxf(acc, 0.f);
    }
}

// ---------------- conv2: (64,32,112,112) -> relu -> (64,64,56,56), s=2 p=1 -----
__global__ __launch_bounds__(256) void conv2_kernel(const float* __restrict__ h1,
        const float* __restrict__ w2, const float* __restrict__ b2,
        float* __restrict__ h2) {
    int pos = blockIdx.x * 256 + threadIdx.x;        // 64*56*56 = 200704
    int b   = pos / (H2 * W2);
    int rem = pos - b * (H2 * W2);
    int oy  = rem / W2;
    int ox  = rem - oy * W2;
    int iy0 = oy * 2 - 1, ix0 = ox * 2 - 1;

    float acc[C2];
    #pragma unroll
    for (int oc = 0; oc < C2; ++oc) acc[oc] = b2[oc];

    for (int c = 0; c < C1; ++c) {                   // 32 input channels
      float win[9];
      #pragma unroll
      for (int dy = 0; dy < 3; ++dy)
        #pragma unroll
        for (int dx = 0; dx < 3; ++dx) {
          int iy = iy0 + dy, ix = ix0 + dx;
          bool ok = (iy >= 0) & (iy < H1) & (ix >= 0) & (ix < W1);
          win[dy*3 + dx] = ok ? h1[((b*C1 + c)*H1 + iy)*W1 + ix] : 0.f;
        }
      #pragma unroll
      for (int oc = 0; oc < C2; ++oc) {
        #pragma unroll
        for (int q = 0; q < 9; ++q)
          acc[oc] = fmaf(w2[(oc*C1 + c)*9 + q], win[q], acc[oc]);
      }
    }
    #pragma unroll
    for (int oc = 0; oc < C2; ++oc)
      h2[((b*C2 + oc)*H2 + oy)*W2 + ox] = fmaxf(acc[oc], 0.f);
}

// ---------------- global average pool: (64,64,56,56) -> feat (64,64) ----------
__global__ __launch_bounds__(256) void pool_kernel(const float* __restrict__ h2,
        float* __restrict__ feat) {
    int bc = blockIdx.x;                             // 0..4095 = b*64 + c
    const float* p = h2 + (size_t)bc * (H2 * W2);
    float s = 0.f;
    for (int i = threadIdx.x; i < H2 * W2; i += 256) s += p[i];
    #pragma unroll
    for (int off = 32; off; off >>= 1) s += __shfl_down(s, off);
    __shared__ float red[4];
    if ((threadIdx.x & 63) == 0) red[threadIdx.x >> 6] = s;
    __syncthreads();
    if (threadIdx.x == 0)
      feat[bc] = (red[0] + red[1] + red[2] + red[3]) * (1.f / (H2 * W2));
}

// ---------------- center: fc = feat - rowmean(feat) ---------------------------
__global__ __launch_bounds__(64) void center_kernel(const float* __restrict__ feat,
        float* __restrict__ fc) {
    __shared__ float fl[FEATN * FEATN];
    int t = threadIdx.x;                             // 64 threads; t = b
    for (int i = t; i < FEATN * FEATN; i += 64) fl[i] = feat[i];
    __syncthreads();
    float m = 0.f;
    for (int c = 0; c < FEATN; ++c) m += fl[t*FEATN + c];
    m *= (1.f / FEATN);
    for (int c = 0; c < FEATN; ++c) fc[t*FEATN + c] = fl[t*FEATN + c] - m;
}

// -------- mean_feat + cov_feat + all biases -> WRITES d_out -------------------
__global__ __launch_bounds__(256) void meancov_kernel(const float* __restrict__ feat,
        const float* __restrict__ fc,
        const float* __restrict__ wm, const float* __restrict__ bm,
        const float* __restrict__ wc, const float* __restrict__ bcv,
        const float* __restrict__ b3, float* __restrict__ out) {
    __shared__ float featT[FEATN * FEATN];           // [c][b]
    __shared__ float fcT[FEATN * FEATN];             // [c][b]
    int t = threadIdx.x;
    for (int i = t; i < FEATN * FEATN; i += 256) {
      int b = i >> 6, c = i & 63;
      featT[c*64 + b] = feat[i];
      fcT[c*64 + b]   = fc[i];
    }
    __syncthreads();

    int b = t & 63;
    int o = blockIdx.x * 4 + (t >> 6);               // 256 blocks * 4 = 1024
    float acc = bm[o] + bcv[o] + b3[o];
    #pragma unroll 8
    for (int c = 0; c < FEATN; ++c)
      acc = fmaf(featT[c*64 + b], wm[o*FEATN + c], acc);
    const float* wcrow = wc + (size_t)o * (FEATN * FEATN);
    for (int c1 = 0; c1 < FEATN; ++c1) {
      float a2 = 0.f;
      #pragma unroll 8
      for (int c2 = 0; c2 < FEATN; ++c2)
        a2 = fmaf(fcT[c2*64 + b], wcrow[c1*64 + c2], a2);
      acc = fmaf(fcT[c1*64 + b], a2, acc);
    }
    out[b * OUTN + o] = acc;
}

// -------- third-order term: C[b,o] += sum_ijk fc_i fc_j fc_k * w3[o,ijk] ------
// bf16 MFMA 16x16x32. A-fragment raw values (fc[b, k-range]) are IDENTICAL for
// every (i,j) pair -> hoisted into 64 VGPRs once per block (loads from global
// fc, L2-resident). Per-ij work: 8 LDS broadcasts (free) + scale/cvt + MFMA.
// Partial sums written non-atomically to ws; reduce_kernel sums 128 slices.
#define NBLKS 16
#define KSLICES 128
#define IJ_PER_BLOCK 32
__global__ __launch_bounds__(256) void third_kernel(const float* __restrict__ fc,
        const float* __restrict__ w3, float* __restrict__ part) {
    __shared__ float fcT[FEATN * FEATN];             // [c][b], broadcast reads
    int t = threadIdx.x;
    for (int i = t; i < FEATN * FEATN; i += 256) {
      int b = i >> 6, k = i & 63;
      fcT[k*64 + b] = fc[i];
    }
    __syncthreads();

    int nblk   = blockIdx.x & (NBLKS - 1);
    int kslice = blockIdx.x >> 4;
    int wave = t >> 6;
    int lane = t & 63;
    int l15  = lane & 15;
    int l4   = lane >> 4;                            // 0..3
    int ocol = nblk*64 + wave*16 + l15;              // output column (o)
    int ijbase = kslice * IJ_PER_BLOCK;

    // Hoisted raw A fragments: lane needs fc[m*16+l15][ (s*4+l4)*8 .. +8 )
    float4 aA[4][2], aB[4][2];                       // 64 VGPRs, static indexing
    #pragma unroll
    for (int m = 0; m < 4; ++m)
      #pragma unroll
      for (int s = 0; s < 2; ++s) {
        const float* p = fc + (m*16 + l15)*64 + (s*4 + l4)*8;
        aA[m][s] = *(const float4*)p;
        aB[m][s] = *(const float4*)(p + 4);
      }

    f32x4 acc[4];
    #pragma unroll
    for (int m = 0; m < 4; ++m) acc[m] = (f32x4){0.f, 0.f, 0.f, 0.f};

    const float* w3col = w3 + (size_t)ocol * K3TOT;

    for (int ij = 0; ij < IJ_PER_BLOCK; ++ij) {
      int ijg = ijbase + ij;
      int i = ijg >> 6, j = ijg & 63;
      // s[m] = fc[b,i]*fc[b,j] for b = m*16 + l15 (broadcast LDS reads, free)
      float smul[4];
      #pragma unroll
      for (int m = 0; m < 4; ++m) {
        int bb = m*16 + l15;
        smul[m] = fcT[i*64 + bb] * fcT[j*64 + bb];
      }
      size_t kb = (size_t)ijg * 64;
      #pragma unroll
      for (int s = 0; s < 2; ++s) {
        // B fragment: w3[ocol, kb + s*32 + l4*8 .. +8)  (128B per 4-lane cluster)
        const float* pw = w3col + kb + s*32 + l4*8;
        float4 b0 = *(const float4*)(pw);
        float4 b1 = *(const float4*)(pw + 4);
        bf16x8 bfrag;
        bfrag[0] = (__bf16)b0.x; bfrag[1] = (__bf16)b0.y;
        bfrag[2] = (__bf16)b0.z; bfrag[3] = (__bf16)b0.w;
        bfrag[4] = (__bf16)b1.x; bfrag[5] = (__bf16)b1.y;
        bfrag[6] = (__bf16)b1.z; bfrag[7] = (__bf16)b1.w;
        #pragma unroll
        for (int m = 0; m < 4; ++m) {
          float sc = smul[m];
          bf16x8 afrag;
          afrag[0] = (__bf16)(aA[m][s].x * sc); afrag[1] = (__bf16)(aA[m][s].y * sc);
          afrag[2] = (__bf16)(aA[m][s].z * sc); afrag[3] = (__bf16)(aA[m][s].w * sc);
          afrag[4] = (__bf16)(aB[m][s].x * sc); afrag[5] = (__bf16)(aB[m][s].y * sc);
          afrag[6] = (__bf16)(aB[m][s].z * sc); afrag[7] = (__bf16)(aB[m][s].w * sc);
          acc[m] = __builtin_amdgcn_mfma_f32_16x16x32_bf16(afrag, bfrag, acc[m], 0, 0, 0);
        }
      }
    }
    // D layout (verified m89): col = lane&15, row = (lane>>4)*4 + reg
    float* pt = part + (size_t)kslice * 64 * OUTN;
    #pragma unroll
    for (int m = 0; m < 4; ++m)
      #pragma unroll
      for (int r = 0; r < 4; ++r) {
        int row = m*16 + l4*4 + r;                   // batch
        pt[row * OUTN + ocol] = acc[m][r];
      }
}

// -------- sum the 128 K-slice partials into d_out ------------------------------
__global__ __launch_bounds__(256) void reduce_kernel(const float* __restrict__ part,
        float* __restrict__ out) {
    int idx = blockIdx.x * 256 + threadIdx.x;        // 65536 = 64*1024
    float s = 0.f;
    #pragma unroll 8
    for (int ks = 0; ks < KSLICES; ++ks)
      s += part[(size_t)ks * (64 * OUTN) + idx];
    out[idx] += s;
}

extern "C" void kernel_launch(void* const* d_in, const int* in_sizes, int n_in,
                              void* d_out, int out_size, void* d_ws, size_t ws_size,
                              hipStream_t stream) {
    const float* x   = (const float*)d_in[0];
    const float* w1  = (const float*)d_in[1];
    const float* b1  = (const float*)d_in[2];
    const float* w2  = (const float*)d_in[3];
    const float* b2  = (const float*)d_in[4];
    const float* wm  = (const float*)d_in[5];
    const float* bm  = (const float*)d_in[6];
    const float* wc  = (const float*)d_in[7];
    const float* bcv = (const float*)d_in[8];
    const float* w3  = (const float*)d_in[9];
    const float* b3  = (const float*)d_in[10];
    float* out = (float*)d_out;

    // workspace layout (floats): h1 | h2 | feat | fc | part  (~186 MB)
    float* ws   = (float*)d_ws;
    float* h1   = ws;                                // 64*32*112*112 = 25690112
    float* h2   = ws + 25690112;                     // 64*64*56*56   = 12845056
    float* feat = ws + 38535168;                     // 4096
    float* fcv  = ws + 38539264;                     // 4096
    float* part = ws + 38543360;                     // 128*64*1024   = 8388608

    conv1_kernel <<<3136, 256, 0, stream>>>(x, w1, b1, h1);
    conv2_kernel <<<784,  256, 0, stream>>>(h1, w2, b2, h2);
    pool_kernel  <<<4096, 256, 0, stream>>>(h2, feat);
    center_kernel<<<1,    64,  0, stream>>>(feat, fcv);
    meancov_kernel<<<256, 256, 0, stream>>>(feat, fcv, wm, bm, wc, bcv, b3, out);
    third_kernel <<<NBLKS * KSLICES, 256, 0, stream>>>(fcv, w3, part);
    reduce_kernel<<<256,  256, 0, stream>>>(part, out);
}

// Round 3
// 707.492 us; speedup vs baseline: 1.0409x; 1.0409x over previous
//
#include <hip/hip_runtime.h>
#include <hip/hip_bf16.h>

// Problem constants
#define BB   64
#define CIN  3
#define HH   224
#define WW   224
#define C1   32
#define H1   112
#define W1   112
#define C2   64
#define H2   56
#define W2   56
#define FEATN 64
#define OUTN 1024
#define K3TOT (FEATN*FEATN*FEATN)   // 262144

typedef __bf16 bf16x8 __attribute__((ext_vector_type(8)));
typedef float  f32x4  __attribute__((ext_vector_type(4)));
typedef unsigned int u32;

__device__ __forceinline__ void gload_lds16(const void* g, void* l) {
  __builtin_amdgcn_global_load_lds((const __attribute__((address_space(1))) u32*)g,
                                   (__attribute__((address_space(3))) u32*)l, 16, 0, 0);
}

// ---------------- conv1: (64,3,224,224) -> relu -> (64,32,112,112), s=2 p=1 ----
__global__ __launch_bounds__(256) void conv1_kernel(const float* __restrict__ x,
        const float* __restrict__ w1, const float* __restrict__ b1,
        float* __restrict__ h1) {
    int pos = blockIdx.x * 256 + threadIdx.x;        // 64*112*112 = 802816
    int b   = pos / (H1 * W1);
    int rem = pos - b * (H1 * W1);
    int oy  = rem / W1;
    int ox  = rem - oy * W1;
    int iy0 = oy * 2 - 1, ix0 = ox * 2 - 1;

    float win[27];
    #pragma unroll
    for (int c = 0; c < CIN; ++c)
      #pragma unroll
      for (int dy = 0; dy < 3; ++dy)
        #pragma unroll
        for (int dx = 0; dx < 3; ++dx) {
          int iy = iy0 + dy, ix = ix0 + dx;
          bool ok = (iy >= 0) & (iy < HH) & (ix >= 0) & (ix < WW);
          win[c*9 + dy*3 + dx] = ok ? x[((b*CIN + c)*HH + iy)*WW + ix] : 0.f;
        }

    #pragma unroll 4
    for (int oc = 0; oc < C1; ++oc) {
      float acc = b1[oc];
      #pragma unroll
      for (int q = 0; q < 27; ++q)
        acc = fmaf(w1[oc*27 + q], win[q], acc);
      h1[((b*C1 + oc)*H1 + oy)*W1 + ox] = fmaxf(acc, 0.f);
    }
}

// ---------------- conv2: (64,32,112,112) -> relu -> (64,64,56,56), s=2 p=1 -----
__global__ __launch_bounds__(256) void conv2_kernel(const float* __restrict__ h1,
        const float* __restrict__ w2, const float* __restrict__ b2,
        float* __restrict__ h2) {
    int pos = blockIdx.x * 256 + threadIdx.x;        // 64*56*56 = 200704
    int b   = pos / (H2 * W2);
    int rem = pos - b * (H2 * W2);
    int oy  = rem / W2;
    int ox  = rem - oy * W2;
    int iy0 = oy * 2 - 1, ix0 = ox * 2 - 1;

    float acc[C2];
    #pragma unroll
    for (int oc = 0; oc < C2; ++oc) acc[oc] = b2[oc];

    for (int c = 0; c < C1; ++c) {                   // 32 input channels
      float win[9];
      #pragma unroll
      for (int dy = 0; dy < 3; ++dy)
        #pragma unroll
        for (int dx = 0; dx < 3; ++dx) {
          int iy = iy0 + dy, ix = ix0 + dx;
          bool ok = (iy >= 0) & (iy < H1) & (ix >= 0) & (ix < W1);
          win[dy*3 + dx] = ok ? h1[((b*C1 + c)*H1 + iy)*W1 + ix] : 0.f;
        }
      #pragma unroll
      for (int oc = 0; oc < C2; ++oc) {
        #pragma unroll
        for (int q = 0; q < 9; ++q)
          acc[oc] = fmaf(w2[(oc*C1 + c)*9 + q], win[q], acc[oc]);
      }
    }
    #pragma unroll
    for (int oc = 0; oc < C2; ++oc)
      h2[((b*C2 + oc)*H2 + oy)*W2 + ox] = fmaxf(acc[oc], 0.f);
}

// ---------------- global average pool: (64,64,56,56) -> feat (64,64) ----------
__global__ __launch_bounds__(256) void pool_kernel(const float* __restrict__ h2,
        float* __restrict__ feat) {
    int bc = blockIdx.x;                             // 0..4095 = b*64 + c
    const float* p = h2 + (size_t)bc * (H2 * W2);
    float s = 0.f;
    for (int i = threadIdx.x; i < H2 * W2; i += 256) s += p[i];
    #pragma unroll
    for (int off = 32; off; off >>= 1) s += __shfl_down(s, off);
    __shared__ float red[4];
    if ((threadIdx.x & 63) == 0) red[threadIdx.x >> 6] = s;
    __syncthreads();
    if (threadIdx.x == 0)
      feat[bc] = (red[0] + red[1] + red[2] + red[3]) * (1.f / (H2 * W2));
}

// ---------------- center: fc = feat - rowmean(feat) ---------------------------
__global__ __launch_bounds__(64) void center_kernel(const float* __restrict__ feat,
        float* __restrict__ fc) {
    __shared__ float fl[FEATN * FEATN];
    int t = threadIdx.x;                             // 64 threads; t = b
    for (int i = t; i < FEATN * FEATN; i += 64) fl[i] = feat[i];
    __syncthreads();
    float m = 0.f;
    for (int c = 0; c < FEATN; ++c) m += fl[t*FEATN + c];
    m *= (1.f / FEATN);
    for (int c = 0; c < FEATN; ++c) fc[t*FEATN + c] = fl[t*FEATN + c] - m;
}

// -------- mean_feat + cov_feat + all biases -> WRITES d_out -------------------
// Inner 4096-iter loop uses 64 REGISTERS for fc row (was: 1 LDS read per fma).
__global__ __launch_bounds__(256) void meancov_kernel(const float* __restrict__ feat,
        const float* __restrict__ fc,
        const float* __restrict__ wm, const float* __restrict__ bm,
        const float* __restrict__ wc, const float* __restrict__ bcv,
        const float* __restrict__ b3, float* __restrict__ out) {
    __shared__ float featT[FEATN * FEATN];           // [c][b]
    __shared__ float fcT[FEATN * FEATN];             // [c][b]
    int t = threadIdx.x;
    for (int i = t; i < FEATN * FEATN; i += 256) {
      int b = i >> 6, c = i & 63;
      featT[c*64 + b] = feat[i];
      fcT[c*64 + b]   = fc[i];
    }
    __syncthreads();

    int b = t & 63;
    int o = blockIdx.x * 4 + (t >> 6);               // 256 blocks * 4 = 1024

    float fr[64];                                    // fc[b][*] in registers
    #pragma unroll
    for (int c4 = 0; c4 < 16; ++c4) {
      float4 v = *(const float4*)(fc + b*64 + c4*4);
      fr[c4*4+0]=v.x; fr[c4*4+1]=v.y; fr[c4*4+2]=v.z; fr[c4*4+3]=v.w;
    }

    float acc = bm[o] + bcv[o] + b3[o];
    #pragma unroll 8
    for (int c = 0; c < FEATN; ++c)
      acc = fmaf(featT[c*64 + b], wm[o*FEATN + c], acc);

    const float* wcrow = wc + (size_t)o * (FEATN * FEATN);
    #pragma unroll 1
    for (int c1 = 0; c1 < 64; ++c1) {
      float a2 = 0.f;
      #pragma unroll
      for (int c2 = 0; c2 < 64; ++c2)                // fr[c2]: static index
        a2 = fmaf(fr[c2], wcrow[c1*64 + c2], a2);
      acc = fmaf(fcT[c1*64 + b], a2, acc);           // LDS: 64 reads total
    }
    out[b * OUTN + o] = acc;
}

// -------- third-order term: C[b,o] += sum_ijk fc_i fc_j fc_k * w3[o,ijk] ------
// Contiguous w3 streaming: global_load_lds (1 KB/inst) into per-wave LDS
// columns, 16-B XOR swizzle (pre-swizzled SOURCE, linear dest, swizzled read),
// double-buffered with counted vmcnt(8). No barriers in the K-loop (each wave
// stages and consumes only its own 16 columns).
// Grid: 32 col-blocks (32 cols each) x 128 K-slices; block = 128 thr (2 waves).
#define T3_NBLK 32
#define KSLICES 128
#define CHUNK_IJ 2
#define NCHUNK 16           // 32 ij-pairs / CHUNK_IJ

struct T3Shared {
    float stage[2][32][CHUNK_IJ*64];   // [buf][block-col][k]  (32 KB)
    float fcJ[32][65];                 // fc[b][jbase+jl] as [jl][b], padded
    float fcI[64];                     // fc[b][i0]
};

__device__ __forceinline__ void t3_issue(const char* w3b, float (*buf)[CHUNK_IJ*64],
        int wave, int ocolbase, size_t kb, int lane) {
    int hi = lane >> 5;                 // which of the 2 cols this lane feeds
    int lo = (lane & 31) * 16;          // byte within the column's 512-B span
    #pragma unroll
    for (int i = 0; i < 8; ++i) {
      int colb = wave*16 + 2*i;         // block-local col of this inst (even)
      int col  = colb + hi;
      // inverse-swizzle the SOURCE so a swizzled READ sees w3[col][kb+koff]
      int srcoff = lo ^ ((col & 7) << 4);
      const char* src = w3b + (((size_t)(ocolbase + col)) << 20) + kb + srcoff;
      gload_lds16(src, &buf[colb][0]);
    }
}

__device__ __forceinline__ void t3_compute(const float (*buf)[CHUNK_IJ*64],
        const float (*fcJ)[65], const float* fcI,
        int c, int wave, int lane, const float4 aA[4][2], const float4 aB[4][2],
        f32x4 acc[4]) {
    int l15 = lane & 15, l4 = lane >> 4;
    int col = wave*16 + l15;
    int swz = (col & 7) << 4;
    int x0 = (l4*32) ^ swz;
    int x1 = (l4*32 + 16) ^ swz;
    const char* p = (const char*)&buf[col][0];
    #pragma unroll
    for (int e = 0; e < CHUNK_IJ; ++e) {
      int jl = c*CHUNK_IJ + e;
      float smul[4];
      #pragma unroll
      for (int m = 0; m < 4; ++m) {
        int bb = m*16 + l15;
        smul[m] = fcI[bb] * fcJ[jl][bb];
      }
      #pragma unroll
      for (int s = 0; s < 2; ++s) {
        int K = e*256 + s*128;                       // static after unroll
        float4 b0 = *(const float4*)(p + K + x0);
        float4 b1 = *(const float4*)(p + K + x1);
        bf16x8 bfrag;
        bfrag[0] = (__bf16)b0.x; bfrag[1] = (__bf16)b0.y;
        bfrag[2] = (__bf16)b0.z; bfrag[3] = (__bf16)b0.w;
        bfrag[4] = (__bf16)b1.x; bfrag[5] = (__bf16)b1.y;
        bfrag[6] = (__bf16)b1.z; bfrag[7] = (__bf16)b1.w;
        #pragma unroll
        for (int m = 0; m < 4; ++m) {
          float sc = smul[m];
          bf16x8 afrag;
          afrag[0] = (__bf16)(aA[m][s].x * sc); afrag[1] = (__bf16)(aA[m][s].y * sc);
          afrag[2] = (__bf16)(aA[m][s].z * sc); afrag[3] = (__bf16)(aA[m][s].w * sc);
          afrag[4] = (__bf16)(aB[m][s].x * sc); afrag[5] = (__bf16)(aB[m][s].y * sc);
          afrag[6] = (__bf16)(aB[m][s].z * sc); afrag[7] = (__bf16)(aB[m][s].w * sc);
          acc[m] = __builtin_amdgcn_mfma_f32_16x16x32_bf16(afrag, bfrag, acc[m], 0, 0, 0);
        }
      }
    }
}

#define T3_WAIT(N) do { asm volatile("s_waitcnt vmcnt(" #N ")" ::: "memory"); \
                        __builtin_amdgcn_sched_barrier(0); } while (0)

__global__ __launch_bounds__(128) void third_kernel(const float* __restrict__ fc,
        const float* __restrict__ w3, float* __restrict__ part) {
    __shared__ T3Shared sh;
    int t = threadIdx.x;
    int nblk   = blockIdx.x & (T3_NBLK - 1);
    int kslice = blockIdx.x >> 5;
    int i0     = kslice >> 1;                        // i is constant per kslice
    int jbase  = (kslice & 1) * 32;

    // stage fcJ (transposed, padded) and fcI
    for (int idx = t; idx < 32*64; idx += 128) {
      int b = idx >> 5, jl = idx & 31;               // contiguous 32-float reads
      sh.fcJ[jl][b] = fc[b*64 + jbase + jl];
    }
    if (t < 64) sh.fcI[t] = fc[t*64 + i0];
    __syncthreads();                                 // drains vmcnt too

    int wave = t >> 6;
    int lane = t & 63;
    int l15  = lane & 15;
    int l4   = lane >> 4;
    int ocolbase = nblk * 32;

    // Hoisted raw A fragments: fc[m*16+l15][(s*4+l4)*8 .. +8)
    float4 aA[4][2], aB[4][2];
    #pragma unroll
    for (int m = 0; m < 4; ++m)
      #pragma unroll
      for (int s = 0; s < 2; ++s) {
        const float* pa = fc + (m*16 + l15)*64 + (s*4 + l4)*8;
        aA[m][s] = *(const float4*)pa;
        aB[m][s] = *(const float4*)(pa + 4);
      }

    f32x4 acc[4];
    #pragma unroll
    for (int m = 0; m < 4; ++m) acc[m] = (f32x4){0.f, 0.f, 0.f, 0.f};

    const char* w3b = (const char*)w3;
    size_t kb0 = (size_t)kslice * 8192;              // byte offset within column
    #define KB(c) (kb0 + (size_t)(c) * (CHUNK_IJ*64*4))

    t3_issue(w3b, sh.stage[0], wave, ocolbase, KB(0), lane);
    #pragma unroll 1
    for (int c = 0; c < NCHUNK - 2; c += 2) {
      t3_issue(w3b, sh.stage[1], wave, ocolbase, KB(c+1), lane);
      T3_WAIT(8);
      t3_compute(sh.stage[0], sh.fcJ, sh.fcI, c, wave, lane, aA, aB, acc);
      t3_issue(w3b, sh.stage[0], wave, ocolbase, KB(c+2), lane);
      T3_WAIT(8);
      t3_compute(sh.stage[1], sh.fcJ, sh.fcI, c+1, wave, lane, aA, aB, acc);
    }
    t3_issue(w3b, sh.stage[1], wave, ocolbase, KB(NCHUNK-1), lane);
    T3_WAIT(8);
    t3_compute(sh.stage[0], sh.fcJ, sh.fcI, NCHUNK-2, wave, lane, aA, aB, acc);
    T3_WAIT(0);
    t3_compute(sh.stage[1], sh.fcJ, sh.fcI, NCHUNK-1, wave, lane, aA, aB, acc);

    // D layout (verified m89): col = lane&15, row = (lane>>4)*4 + reg
    float* pt = part + (size_t)kslice * 64 * OUTN;
    int ocol = ocolbase + wave*16 + l15;
    #pragma unroll
    for (int m = 0; m < 4; ++m)
      #pragma unroll
      for (int r = 0; r < 4; ++r) {
        int row = m*16 + l4*4 + r;                   // batch
        pt[row * OUTN + ocol] = acc[m][r];
      }
}

// -------- sum the 128 K-slice partials into d_out ------------------------------
__global__ __launch_bounds__(256) void reduce_kernel(const float* __restrict__ part,
        float* __restrict__ out) {
    int idx = blockIdx.x * 256 + threadIdx.x;        // 65536 = 64*1024
    float s = 0.f;
    #pragma unroll 8
    for (int ks = 0; ks < KSLICES; ++ks)
      s += part[(size_t)ks * (64 * OUTN) + idx];
    out[idx] += s;
}

extern "C" void kernel_launch(void* const* d_in, const int* in_sizes, int n_in,
                              void* d_out, int out_size, void* d_ws, size_t ws_size,
                              hipStream_t stream) {
    const float* x   = (const float*)d_in[0];
    const float* w1  = (const float*)d_in[1];
    const float* b1  = (const float*)d_in[2];
    const float* w2  = (const float*)d_in[3];
    const float* b2  = (const float*)d_in[4];
    const float* wm  = (const float*)d_in[5];
    const float* bm  = (const float*)d_in[6];
    const float* wc  = (const float*)d_in[7];
    const float* bcv = (const float*)d_in[8];
    const float* w3  = (const float*)d_in[9];
    const float* b3  = (const float*)d_in[10];
    float* out = (float*)d_out;

    // workspace layout (floats): h1 | h2 | feat | fc | part  (~188 MB)
    float* ws   = (float*)d_ws;
    float* h1   = ws;                                // 64*32*112*112 = 25690112
    float* h2   = ws + 25690112;                     // 64*64*56*56   = 12845056
    float* feat = ws + 38535168;                     // 4096
    float* fcv  = ws + 38539264;                     // 4096
    float* part = ws + 38543360;                     // 128*64*1024   = 8388608

    conv1_kernel <<<3136, 256, 0, stream>>>(x, w1, b1, h1);
    conv2_kernel <<<784,  256, 0, stream>>>(h1, w2, b2, h2);
    pool_kernel  <<<4096, 256, 0, stream>>>(h2, feat);
    center_kernel<<<1,    64,  0, stream>>>(feat, fcv);
    meancov_kernel<<<256, 256, 0, stream>>>(feat, fcv, wm, bm, wc, bcv, b3, out);
    third_kernel <<<T3_NBLK * KSLICES, 128, 0, stream>>>(fcv, w3, part);
    reduce_kernel<<<256,  256, 0, stream>>>(part, out);
}